// Round 2
// baseline (406.799 us; speedup 1.0000x reference)
//
#include <hip/hip_runtime.h>

typedef __attribute__((ext_vector_type(8))) short short8;
typedef __attribute__((ext_vector_type(4))) float f32x4;
union frag_u { short8 v; unsigned short u[8]; };

__device__ __forceinline__ float bf2f(unsigned short b) {
  unsigned int u = ((unsigned int)b) << 16;
  float f; __builtin_memcpy(&f, &u, 4); return f;
}
__device__ __forceinline__ unsigned short f2bf(float f) {
  unsigned int u; __builtin_memcpy(&u, &f, 4);
  return (unsigned short)((u + 0x7FFFu + ((u >> 16) & 1u)) >> 16);
}
__device__ __forceinline__ unsigned short hi_of(float f) { return f2bf(f); }
__device__ __forceinline__ unsigned short lo_of(float f) {
  unsigned short h = f2bf(f); return f2bf(f - bf2f(h));
}
__device__ __forceinline__ float sigm(float x) {
  return __builtin_amdgcn_rcpf(1.f + __expf(-x));
}
__device__ __forceinline__ float tanh_(float x) {
  return 1.f - 2.f * __builtin_amdgcn_rcpf(1.f + __expf(2.f * x));
}

// dtype detector: even-indexed uint16s of an f32 buffer are uniform mantissa
// halves (mostly insane bf16 exponents); of a bf16 buffer they are N(0,1)
// values (sane exponents 100..140). flag: 0 = bf16, 1 = f32.
__global__ void detect_dtype_kernel(const unsigned short* s, int* flag) {
  if (threadIdx.x == 0 && blockIdx.x == 0) {
    int insane = 0;
    for (int i = 0; i < 64; ++i) {
      unsigned short v = s[2 * i];
      int e = (v >> 7) & 0xFF;
      if (e < 100 || e > 140) insane++;
    }
    *flag = (insane >= 16) ? 1 : 0;
  }
}

// sA(16 x Kpad bf16, stride AS) @ W(K x N) -> sG[n][m]  (G stride 20)
// A-frag: lane holds A[m=lane&15][k=kc*32+quad*8+j]; B-frag: W[k][n=tile*16+(lane&15)]
// C/D: row m = quad*4+reg, col n = lane&15   [verified m89/m91]
template <int AS, typename GetB, typename GetW>
__device__ __forceinline__ void mfma_layer(const unsigned short* sA, float* sG,
    int wave, int col, int quad, int kc_n, int ntiles, int N, GetB getb, GetW getw)
{
  for (int tile = wave; tile < ntiles; tile += 4) {
    int n = tile * 16 + col;
    float b = (n < N) ? getb(n) : 0.f;
    f32x4 acc = {b, b, b, b};
    for (int kc = 0; kc < kc_n; ++kc) {
      short8 a = *(const short8*)&sA[col * AS + kc * 32 + quad * 8];
      frag_u w;
      #pragma unroll
      for (int j = 0; j < 8; ++j) {
        int k = kc * 32 + quad * 8 + j;
        w.u[j] = (n < N) ? getw(k, n) : (unsigned short)0;
      }
      acc = __builtin_amdgcn_mfma_f32_16x16x32_bf16(a, w.v, acc, 0, 0, 0);
    }
    *(f32x4*)&sG[n * 20 + quad * 4] = acc;
  }
}

// relu(sG col) -> sA as bf16 hi at [0,N), optional lo at [loOff,loOff+N), zero pad to Kpad
template <int AS, bool LO>
__device__ __forceinline__ void relu_fill(const float* sG, unsigned short* sA,
                                          int tid, int N, int loOff, int Kpad) {
  for (int idx = tid; idx < 16 * Kpad; idx += 256) {
    int m = idx & 15, n = idx >> 4;
    unsigned short v = 0;
    if (n < N) {
      v = f2bf(fmaxf(sG[n * 20 + m], 0.f));
    } else if (LO && n >= loOff && n < loOff + N) {
      float x = fmaxf(sG[(n - loOff) * 20 + m], 0.f);
      v = lo_of(x);
    }
    sA[m * AS + n] = v;
  }
}

// ROWS_PER_BLOCK = 8 (upper 8 MFMA rows are wasted — we are latency-bound,
// not MFMA-bound; halving rows doubles the grid to 1024 -> 4 blocks/CU).
template <bool F32>
__global__ __launch_bounds__(256) void value_net_kernel(
    const void* state_, const void* wih_, const void* whh_,
    const void* bih_, const void* bhh_,
    const void* w1_, const void* b1_, const void* w2_, const void* b2_,
    const void* w3_, const void* b3_, const void* w4_, const void* b4_,
    void* out_, const int* flag)
{
  if (flag && *flag != (F32 ? 1 : 0)) return;   // dtype mismatch -> other variant runs

  // A column layout, LSTM phase:
  //  bf16: [x(0..6) | h_hi(7..56) | h_lo(57..106) | 0-pad..127]           K=4x32
  //  f32 : [x_hi(0..6) | x_lo(7..13) | x_hi(14..20) | h_hi(21..70) |
  //         h_lo(71..120) | h_hi(121..170) | 0-pad..191]                  K=6x32
  //        paired with W rows [Wx_hi|Wx_hi|Wx_lo|Wh_hi|Wh_hi|Wh_lo] (tri-product)
  constexpr int AS = F32 ? 328 : 168;   // max Kpad (+8 pad): f32 L2 needs 320
  constexpr int KC = F32 ? 6 : 4;

  __shared__ __align__(16) unsigned short sA[16 * AS];
  __shared__ __align__(16) float sG[208 * 20];

  const unsigned short* st16 = (const unsigned short*)state_;
  const float*          stf  = (const float*)state_;

  const int tid  = threadIdx.x;
  const int wave = tid >> 6;
  const int lane = tid & 63;
  const int col  = lane & 15;
  const int quad = lane >> 4;
  const int r0   = blockIdx.x * 8;      // 8 rows per block

  // ---- zero sA (h0 = 0 and all K padding; rows 8..15 stay zero forever) ----
  {
    unsigned int* a32 = (unsigned int*)sA;
    constexpr int ZN = (16 * AS / 2 + 255) / 256;
    #pragma unroll
    for (int i = 0; i < ZN; ++i) {
      int idx = tid + i * 256;
      if (idx < 16 * AS / 2) a32[idx] = 0;
    }
  }

  // ---- LSTM weight getter ----
  auto W_lstm = [&](int k, int n) -> unsigned short {
    if constexpr (!F32) {
      const unsigned short* wih = (const unsigned short*)wih_;
      const unsigned short* whh = (const unsigned short*)whh_;
      if (k < 7)   return wih[k * 200 + n];
      if (k < 57)  return whh[(k - 7) * 200 + n];
      if (k < 107) return whh[(k - 57) * 200 + n];
      return (unsigned short)0;
    } else {
      const float* wih = (const float*)wih_;
      const float* whh = (const float*)whh_;
      if (k < 7)   return hi_of(wih[k * 200 + n]);
      if (k < 14)  return hi_of(wih[(k - 7) * 200 + n]);
      if (k < 21)  return lo_of(wih[(k - 14) * 200 + n]);
      if (k < 71)  return hi_of(whh[(k - 21) * 200 + n]);
      if (k < 121) return hi_of(whh[(k - 71) * 200 + n]);
      if (k < 171) return lo_of(whh[(k - 121) * 200 + n]);
      return (unsigned short)0;
    }
  };
  auto ldf = [&](const void* p, int i) -> float {
    if constexpr (F32) return ((const float*)p)[i];
    else               return bf2f(((const unsigned short*)p)[i]);
  };

  // ---- persistent LSTM weight fragments: 13 N-tiles over 4 waves ----
  const int nmine = (wave == 0) ? 4 : 3;
  frag_u wf[4][KC];
  float  wb[4];
  #pragma unroll
  for (int i = 0; i < 4; ++i) {
    if (i >= nmine) continue;
    int n = (wave + 4 * i) * 16 + col;
    #pragma unroll
    for (int kc = 0; kc < KC; ++kc) {
      #pragma unroll
      for (int j = 0; j < 8; ++j) {
        int k = kc * 32 + quad * 8 + j;
        wf[i][kc].u[j] = (n < 200) ? W_lstm(k, n) : (unsigned short)0;
      }
    }
    wb[i] = (n < 200) ? (ldf(bih_, n) + ldf(bhh_, n)) : 0.f;
  }

  // ---- activation work items: idx = u*8 + m, 400 over 256 threads ----
  int im[2], iu[2]; bool iv[2];
  float c_[2] = {0.f, 0.f}, hf[2] = {0.f, 0.f};
  #pragma unroll
  for (int i = 0; i < 2; ++i) {
    int idx = tid + 256 * i;
    iv[i] = idx < 400; im[i] = idx & 7; iu[i] = idx >> 3;
  }
  const int  xm = tid / 7, xd = tid - (tid / 7) * 7;
  const bool isx = tid < 56;            // 8 rows x 7 dims
  auto xgidx = [&](int t) -> size_t { return (size_t)(r0 + xm) * 832 + t * 13 + 6 + xd; };
  auto xwrite = [&](float fv, unsigned short bv) {
    if constexpr (!F32) { sA[xm * AS + xd] = bv; }
    else {
      unsigned short h = f2bf(fv);
      sA[xm * AS + xd] = h; sA[xm * AS + 14 + xd] = h;
      sA[xm * AS + 7 + xd] = f2bf(fv - bf2f(h));
    }
  };

  unsigned short xv16 = 0; float xvf = 0.f;   // prefetched x_{t+1}

  __syncthreads();
  if (isx) {   // x_0 + prefetch x_1
    if constexpr (!F32) { xwrite(0.f, st16[xgidx(0)]); xv16 = st16[xgidx(1)]; }
    else                { xwrite(stf[xgidx(0)], 0);    xvf  = stf[xgidx(1)]; }
  }
  __syncthreads();

  // ---- LSTM: 64 steps ----
  for (int t = 0; t < 64; ++t) {
    short8 a[KC];
    #pragma unroll
    for (int kc = 0; kc < KC; ++kc)
      a[kc] = *(const short8*)&sA[col * AS + kc * 32 + quad * 8];
    #pragma unroll
    for (int i = 0; i < 4; ++i) {
      if (i < nmine) {
        float b = wb[i];
        f32x4 acc = {b, b, b, b};
        #pragma unroll
        for (int kc = 0; kc < KC; ++kc)
          acc = __builtin_amdgcn_mfma_f32_16x16x32_bf16(a[kc], wf[i][kc].v, acc, 0, 0, 0);
        int n = (wave + 4 * i) * 16 + col;
        *(f32x4*)&sG[n * 20 + quad * 4] = acc;
      }
    }
    __syncthreads();
    #pragma unroll
    for (int i = 0; i < 2; ++i) {
      if (iv[i]) {
        int m = im[i], u = iu[i];
        float gi = sG[u * 20 + m];
        float gf = sG[(50 + u) * 20 + m];
        float gg = sG[(100 + u) * 20 + m];
        float go = sG[(150 + u) * 20 + m];
        float cc = sigm(gf) * c_[i] + sigm(gi) * tanh_(gg);
        c_[i] = cc;
        float h = sigm(go) * tanh_(cc);
        if (t < 63) {
          unsigned short hb = f2bf(h);
          unsigned short hl = f2bf(h - bf2f(hb));
          if constexpr (!F32) { sA[m * AS + 7 + u] = hb; sA[m * AS + 57 + u] = hl; }
          else { sA[m * AS + 21 + u] = hb; sA[m * AS + 121 + u] = hb; sA[m * AS + 71 + u] = hl; }
        } else hf[i] = h;
      }
    }
    if (isx && t < 63) {
      if constexpr (!F32) xwrite(0.f, xv16); else xwrite(xvf, 0);
      if (t < 62) { if constexpr (!F32) xv16 = st16[xgidx(t + 2)]; else xvf = stf[xgidx(t + 2)]; }
    }
    __syncthreads();
  }

  // ---- tail MLP, fused ----
  // joint cols: bf16 [self(0..5)|h_hi(6..55)|h_lo(56..105)] K=106->128
  //             f32  [self_hi(0..5)|h_hi(6..55)|self_lo(56..61)|h_lo(62..111)] K=112->128
  {
    unsigned int* a32 = (unsigned int*)sA;
    constexpr int ZN = (16 * AS / 2 + 255) / 256;
    #pragma unroll
    for (int i = 0; i < ZN; ++i) {
      int idx = tid + i * 256;
      if (idx < 16 * AS / 2) a32[idx] = 0;
    }
  }
  __syncthreads();
  #pragma unroll
  for (int i = 0; i < 2; ++i) {
    if (iv[i]) {
      int m = im[i], u = iu[i];
      unsigned short hb = f2bf(hf[i]);
      unsigned short hl = f2bf(hf[i] - bf2f(hb));
      sA[m * AS + 6 + u] = hb;
      if constexpr (!F32) sA[m * AS + 56 + u] = hl; else sA[m * AS + 62 + u] = hl;
    }
  }
  if (tid < 48) {                        // 8 rows x 6 self dims
    int m = tid / 6, d = tid - (tid / 6) * 6;
    if constexpr (!F32) sA[m * AS + d] = st16[(size_t)(r0 + m) * 832 + d];
    else {
      float f = stf[(size_t)(r0 + m) * 832 + d];
      sA[m * AS + d] = hi_of(f); sA[m * AS + 56 + d] = lo_of(f);
    }
  }
  __syncthreads();

  // L1: -> 150
  mfma_layer<AS>(sA, sG, wave, col, quad, 4, 10, 150,
    [&](int n) { return ldf(b1_, n); },
    [&](int k, int n) -> unsigned short {
      if constexpr (!F32) {
        const unsigned short* w1 = (const unsigned short*)w1_;
        if (k < 56)  return w1[k * 150 + n];
        if (k < 106) return w1[(k - 50) * 150 + n];
        return (unsigned short)0;
      } else {
        const float* w1 = (const float*)w1_;
        if (k < 56)  return hi_of(w1[k * 150 + n]);
        if (k < 112) return hi_of(w1[(k - 56) * 150 + n]);
        return (unsigned short)0;
      }
    });
  __syncthreads();
  if constexpr (!F32) relu_fill<AS, false>(sG, sA, tid, 150, 160, 160);
  else                relu_fill<AS, true >(sG, sA, tid, 150, 150, 320);
  __syncthreads();

  // L2: 150 -> 100
  mfma_layer<AS>(sA, sG, wave, col, quad, F32 ? 10 : 5, 7, 100,
    [&](int n) { return ldf(b2_, n); },
    [&](int k, int n) -> unsigned short {
      if constexpr (!F32) {
        const unsigned short* w2 = (const unsigned short*)w2_;
        return (k < 150) ? w2[k * 100 + n] : (unsigned short)0;
      } else {
        const float* w2 = (const float*)w2_;
        if (k < 150) return hi_of(w2[k * 100 + n]);
        if (k < 300) return hi_of(w2[(k - 150) * 100 + n]);
        return (unsigned short)0;
      }
    });
  __syncthreads();
  if constexpr (!F32) relu_fill<AS, false>(sG, sA, tid, 100, 128, 128);
  else                relu_fill<AS, true >(sG, sA, tid, 100, 100, 224);
  __syncthreads();

  // L3: 100 -> 100
  mfma_layer<AS>(sA, sG, wave, col, quad, F32 ? 7 : 4, 7, 100,
    [&](int n) { return ldf(b3_, n); },
    [&](int k, int n) -> unsigned short {
      if constexpr (!F32) {
        const unsigned short* w3 = (const unsigned short*)w3_;
        return (k < 100) ? w3[k * 100 + n] : (unsigned short)0;
      } else {
        const float* w3 = (const float*)w3_;
        if (k < 100) return hi_of(w3[k * 100 + n]);
        if (k < 200) return hi_of(w3[(k - 100) * 100 + n]);
        return (unsigned short)0;
      }
    });
  __syncthreads();

  // L4: relu(sG) @ w4 + b4, f32 VALU, 16-lane shuffle reduce (rows 0..7 only)
  {
    int m = tid >> 4, j0 = tid & 15;
    float s = 0.f;
    for (int j = j0; j < 100; j += 16)
      s += fmaxf(sG[j * 20 + m], 0.f) * ldf(w4_, j);
    s += __shfl_xor(s, 8); s += __shfl_xor(s, 4);
    s += __shfl_xor(s, 2); s += __shfl_xor(s, 1);
    if (j0 == 0 && m < 8) {
      float v = s + ldf(b4_, 0);
      if constexpr (!F32) ((unsigned short*)out_)[r0 + m] = f2bf(v);
      else                ((float*)out_)[r0 + m] = v;
    }
  }
}

extern "C" void kernel_launch(void* const* d_in, const int* in_sizes, int n_in,
                              void* d_out, int out_size, void* d_ws, size_t ws_size,
                              hipStream_t stream) {
  (void)in_sizes; (void)n_in; (void)out_size;
  // d_in[1..10] (mlp1_* / attn_*) are dead code in the reference — unused.
  const void* state = d_in[0];
  const void* wih = d_in[11]; const void* whh = d_in[12];
  const void* bih = d_in[13]; const void* bhh = d_in[14];
  const void* w1  = d_in[15]; const void* b1  = d_in[16];
  const void* w2  = d_in[17]; const void* b2  = d_in[18];
  const void* w3  = d_in[19]; const void* b3  = d_in[20];
  const void* w4  = d_in[21]; const void* b4  = d_in[22];

  if (ws_size >= sizeof(int)) {
    int* flag = (int*)d_ws;
    detect_dtype_kernel<<<dim3(1), dim3(64), 0, stream>>>(
        (const unsigned short*)state, flag);
    value_net_kernel<false><<<dim3(1024), dim3(256), 0, stream>>>(
        state, wih, whh, bih, bhh, w1, b1, w2, b2, w3, b3, w4, b4, d_out, flag);
    value_net_kernel<true><<<dim3(1024), dim3(256), 0, stream>>>(
        state, wih, whh, bih, bhh, w1, b1, w2, b2, w3, b3, w4, b4, d_out, flag);
  } else {
    value_net_kernel<false><<<dim3(1024), dim3(256), 0, stream>>>(
        state, wih, whh, bih, bhh, w1, b1, w2, b2, w3, b3, w4, b4, d_out,
        (const int*)nullptr);
  }
}

// Round 3
// 243.809 us; speedup vs baseline: 1.6685x; 1.6685x over previous
//
#include <hip/hip_runtime.h>

typedef __attribute__((ext_vector_type(8))) short short8;
typedef __attribute__((ext_vector_type(4))) float f32x4;
union frag_u { short8 v; unsigned short u[8]; };

__device__ __forceinline__ float bf2f(unsigned short b) {
  unsigned int u = ((unsigned int)b) << 16;
  float f; __builtin_memcpy(&f, &u, 4); return f;
}
__device__ __forceinline__ unsigned short f2bf(float f) {
  unsigned int u; __builtin_memcpy(&u, &f, 4);
  return (unsigned short)((u + 0x7FFFu + ((u >> 16) & 1u)) >> 16);
}
__device__ __forceinline__ unsigned short hi_of(float f) { return f2bf(f); }
__device__ __forceinline__ unsigned short lo_of(float f) {
  unsigned short h = f2bf(f); return f2bf(f - bf2f(h));
}
__device__ __forceinline__ float sigm(float x) {
  return __builtin_amdgcn_rcpf(1.f + __expf(-x));
}
__device__ __forceinline__ float tanh_(float x) {
  return 1.f - 2.f * __builtin_amdgcn_rcpf(1.f + __expf(2.f * x));
}

// dtype detector: even-indexed uint16s of an f32 buffer are uniform mantissa
// halves (mostly insane bf16 exponents); of a bf16 buffer they are N(0,1)
// values (sane exponents 100..140). flag: 0 = bf16, 1 = f32.
__global__ void detect_dtype_kernel(const unsigned short* s, int* flag) {
  if (threadIdx.x == 0 && blockIdx.x == 0) {
    int insane = 0;
    for (int i = 0; i < 64; ++i) {
      unsigned short v = s[2 * i];
      int e = (v >> 7) & 0xFF;
      if (e < 100 || e > 140) insane++;
    }
    *flag = (insane >= 16) ? 1 : 0;
  }
}

// sA(16 x Kpad bf16, stride AS) @ W(K x N) -> sG[n][m]  (G stride 20)
// A-frag: lane holds A[m=lane&15][k=kc*32+quad*8+j]; B-frag: W[k][n=tile*16+(lane&15)]
// C/D: row m = quad*4+reg, col n = lane&15   [verified m89/m91]
// 8 waves: tiles strided by 8.
template <int AS, typename GetB, typename GetW>
__device__ __forceinline__ void mfma_layer(const unsigned short* sA, float* sG,
    int wave, int col, int quad, int kc_n, int ntiles, int N, GetB getb, GetW getw)
{
  for (int tile = wave; tile < ntiles; tile += 8) {
    int n = tile * 16 + col;
    float b = (n < N) ? getb(n) : 0.f;
    f32x4 acc = {b, b, b, b};
    for (int kc = 0; kc < kc_n; ++kc) {
      short8 a = *(const short8*)&sA[col * AS + kc * 32 + quad * 8];
      frag_u w;
      #pragma unroll
      for (int j = 0; j < 8; ++j) {
        int k = kc * 32 + quad * 8 + j;
        w.u[j] = (n < N) ? getw(k, n) : (unsigned short)0;
      }
      acc = __builtin_amdgcn_mfma_f32_16x16x32_bf16(a, w.v, acc, 0, 0, 0);
    }
    *(f32x4*)&sG[n * 20 + quad * 4] = acc;
  }
}

// relu(sG col) -> sA as bf16 hi at [0,N), optional lo at [loOff,loOff+N), zero pad to Kpad
template <int AS, bool LO>
__device__ __forceinline__ void relu_fill(const float* sG, unsigned short* sA,
                                          int tid, int N, int loOff, int Kpad) {
  for (int idx = tid; idx < 16 * Kpad; idx += 512) {
    int m = idx & 15, n = idx >> 4;
    unsigned short v = 0;
    if (n < N) {
      v = f2bf(fmaxf(sG[n * 20 + m], 0.f));
    } else if (LO && n >= loOff && n < loOff + N) {
      float x = fmaxf(sG[(n - loOff) * 20 + m], 0.f);
      v = lo_of(x);
    }
    sA[m * AS + n] = v;
  }
}

// 512 threads / 8 waves per block, 16 rows per block, grid = 512.
// 13 gate-tiles over 8 waves -> wf[2][KC] = half the persistent weight
// registers of the 4-wave version; __launch_bounds__(512,4) forces <=128
// VGPR so 2 blocks (16 waves) fit per CU.
template <bool F32>
__global__ __launch_bounds__(512, 4) void value_net_kernel(
    const void* state_, const void* wih_, const void* whh_,
    const void* bih_, const void* bhh_,
    const void* w1_, const void* b1_, const void* w2_, const void* b2_,
    const void* w3_, const void* b3_, const void* w4_, const void* b4_,
    void* out_, const int* flag)
{
  if (flag && *flag != (F32 ? 1 : 0)) return;   // dtype mismatch -> other variant runs

  // A column layout, LSTM phase:
  //  bf16: [x(0..6) | h_hi(7..56) | h_lo(57..106) | 0-pad..127]           K=4x32
  //  f32 : [x_hi(0..6) | x_lo(7..13) | x_hi(14..20) | h_hi(21..70) |
  //         h_lo(71..120) | h_hi(121..170) | 0-pad..191]                  K=6x32
  //        paired with W rows [Wx_hi|Wx_hi|Wx_lo|Wh_hi|Wh_hi|Wh_lo] (tri-product)
  constexpr int AS = F32 ? 328 : 168;   // max Kpad (+8 pad): f32 L2 needs 320
  constexpr int KC = F32 ? 6 : 4;

  __shared__ __align__(16) unsigned short sA[16 * AS];
  __shared__ __align__(16) float sG[208 * 20];

  const unsigned short* st16 = (const unsigned short*)state_;
  const float*          stf  = (const float*)state_;

  const int tid  = threadIdx.x;
  const int wave = tid >> 6;            // 0..7
  const int lane = tid & 63;
  const int col  = lane & 15;
  const int quad = lane >> 4;
  const int r0   = blockIdx.x * 16;

  // ---- zero sA (h0 = 0 and all K padding) ----
  {
    unsigned int* a32 = (unsigned int*)sA;
    constexpr int ZN = (16 * AS / 2 + 511) / 512;
    #pragma unroll
    for (int i = 0; i < ZN; ++i) {
      int idx = tid + i * 512;
      if (idx < 16 * AS / 2) a32[idx] = 0;
    }
  }

  // ---- LSTM weight getter ----
  auto W_lstm = [&](int k, int n) -> unsigned short {
    if constexpr (!F32) {
      const unsigned short* wih = (const unsigned short*)wih_;
      const unsigned short* whh = (const unsigned short*)whh_;
      if (k < 7)   return wih[k * 200 + n];
      if (k < 57)  return whh[(k - 7) * 200 + n];
      if (k < 107) return whh[(k - 57) * 200 + n];
      return (unsigned short)0;
    } else {
      const float* wih = (const float*)wih_;
      const float* whh = (const float*)whh_;
      if (k < 7)   return hi_of(wih[k * 200 + n]);
      if (k < 14)  return hi_of(wih[(k - 7) * 200 + n]);
      if (k < 21)  return lo_of(wih[(k - 14) * 200 + n]);
      if (k < 71)  return hi_of(whh[(k - 21) * 200 + n]);
      if (k < 121) return hi_of(whh[(k - 71) * 200 + n]);
      if (k < 171) return lo_of(whh[(k - 121) * 200 + n]);
      return (unsigned short)0;
    }
  };
  auto ldf = [&](const void* p, int i) -> float {
    if constexpr (F32) return ((const float*)p)[i];
    else               return bf2f(((const unsigned short*)p)[i]);
  };

  // ---- persistent LSTM weight fragments: 13 N-tiles over 8 waves ----
  // wave w owns tiles w and w+8 (second valid for w<5).
  const int nmine = (wave < 5) ? 2 : 1;
  frag_u wf[2][KC];
  float  wb[2];
  #pragma unroll
  for (int i = 0; i < 2; ++i) {
    if (i >= nmine) continue;
    int n = (wave + 8 * i) * 16 + col;
    #pragma unroll
    for (int kc = 0; kc < KC; ++kc) {
      #pragma unroll
      for (int j = 0; j < 8; ++j) {
        int k = kc * 32 + quad * 8 + j;
        wf[i][kc].u[j] = (n < 200) ? W_lstm(k, n) : (unsigned short)0;
      }
    }
    wb[i] = (n < 200) ? (ldf(bih_, n) + ldf(bhh_, n)) : 0.f;
  }

  // ---- activation work items: idx = u*16 + m, 800 over 512 threads ----
  int im[2], iu[2]; bool iv[2];
  float c_[2] = {0.f, 0.f}, hf[2] = {0.f, 0.f};
  #pragma unroll
  for (int i = 0; i < 2; ++i) {
    int idx = tid + 512 * i;
    iv[i] = idx < 800; im[i] = idx & 15; iu[i] = idx >> 4;
  }
  const int  xm = tid / 7, xd = tid - (tid / 7) * 7;
  const bool isx = tid < 112;
  auto xgidx = [&](int t) -> size_t { return (size_t)(r0 + xm) * 832 + t * 13 + 6 + xd; };
  auto xwrite = [&](float fv, unsigned short bv) {
    if constexpr (!F32) { sA[xm * AS + xd] = bv; }
    else {
      unsigned short h = f2bf(fv);
      sA[xm * AS + xd] = h; sA[xm * AS + 14 + xd] = h;
      sA[xm * AS + 7 + xd] = f2bf(fv - bf2f(h));
    }
  };

  unsigned short xv16 = 0; float xvf = 0.f;   // prefetched x_{t+1}

  __syncthreads();
  if (isx) {   // x_0 + prefetch x_1
    if constexpr (!F32) { xwrite(0.f, st16[xgidx(0)]); xv16 = st16[xgidx(1)]; }
    else                { xwrite(stf[xgidx(0)], 0);    xvf  = stf[xgidx(1)]; }
  }
  __syncthreads();

  // ---- LSTM: 64 steps ----
  for (int t = 0; t < 64; ++t) {
    short8 a[KC];
    #pragma unroll
    for (int kc = 0; kc < KC; ++kc)
      a[kc] = *(const short8*)&sA[col * AS + kc * 32 + quad * 8];
    #pragma unroll
    for (int i = 0; i < 2; ++i) {
      if (i < nmine) {
        float b = wb[i];
        f32x4 acc = {b, b, b, b};
        #pragma unroll
        for (int kc = 0; kc < KC; ++kc)
          acc = __builtin_amdgcn_mfma_f32_16x16x32_bf16(a[kc], wf[i][kc].v, acc, 0, 0, 0);
        int n = (wave + 8 * i) * 16 + col;
        *(f32x4*)&sG[n * 20 + quad * 4] = acc;
      }
    }
    __syncthreads();
    #pragma unroll
    for (int i = 0; i < 2; ++i) {
      if (iv[i]) {
        int m = im[i], u = iu[i];
        float gi = sG[u * 20 + m];
        float gf = sG[(50 + u) * 20 + m];
        float gg = sG[(100 + u) * 20 + m];
        float go = sG[(150 + u) * 20 + m];
        float cc = sigm(gf) * c_[i] + sigm(gi) * tanh_(gg);
        c_[i] = cc;
        float h = sigm(go) * tanh_(cc);
        if (t < 63) {
          unsigned short hb = f2bf(h);
          unsigned short hl = f2bf(h - bf2f(hb));
          if constexpr (!F32) { sA[m * AS + 7 + u] = hb; sA[m * AS + 57 + u] = hl; }
          else { sA[m * AS + 21 + u] = hb; sA[m * AS + 121 + u] = hb; sA[m * AS + 71 + u] = hl; }
        } else hf[i] = h;
      }
    }
    if (isx && t < 63) {
      if constexpr (!F32) xwrite(0.f, xv16); else xwrite(xvf, 0);
      if (t < 62) { if constexpr (!F32) xv16 = st16[xgidx(t + 2)]; else xvf = stf[xgidx(t + 2)]; }
    }
    __syncthreads();
  }

  // ---- tail MLP, fused ----
  // joint cols: bf16 [self(0..5)|h_hi(6..55)|h_lo(56..105)] K=106->128
  //             f32  [self_hi(0..5)|h_hi(6..55)|self_lo(56..61)|h_lo(62..111)] K=112->128
  {
    unsigned int* a32 = (unsigned int*)sA;
    constexpr int ZN = (16 * AS / 2 + 511) / 512;
    #pragma unroll
    for (int i = 0; i < ZN; ++i) {
      int idx = tid + i * 512;
      if (idx < 16 * AS / 2) a32[idx] = 0;
    }
  }
  __syncthreads();
  #pragma unroll
  for (int i = 0; i < 2; ++i) {
    if (iv[i]) {
      int m = im[i], u = iu[i];
      unsigned short hb = f2bf(hf[i]);
      unsigned short hl = f2bf(hf[i] - bf2f(hb));
      sA[m * AS + 6 + u] = hb;
      if constexpr (!F32) sA[m * AS + 56 + u] = hl; else sA[m * AS + 62 + u] = hl;
    }
  }
  if (tid < 96) {
    int m = tid / 6, d = tid - (tid / 6) * 6;
    if constexpr (!F32) sA[m * AS + d] = st16[(size_t)(r0 + m) * 832 + d];
    else {
      float f = stf[(size_t)(r0 + m) * 832 + d];
      sA[m * AS + d] = hi_of(f); sA[m * AS + 56 + d] = lo_of(f);
    }
  }
  __syncthreads();

  // L1: -> 150
  mfma_layer<AS>(sA, sG, wave, col, quad, 4, 10, 150,
    [&](int n) { return ldf(b1_, n); },
    [&](int k, int n) -> unsigned short {
      if constexpr (!F32) {
        const unsigned short* w1 = (const unsigned short*)w1_;
        if (k < 56)  return w1[k * 150 + n];
        if (k < 106) return w1[(k - 50) * 150 + n];
        return (unsigned short)0;
      } else {
        const float* w1 = (const float*)w1_;
        if (k < 56)  return hi_of(w1[k * 150 + n]);
        if (k < 112) return hi_of(w1[(k - 56) * 150 + n]);
        return (unsigned short)0;
      }
    });
  __syncthreads();
  if constexpr (!F32) relu_fill<AS, false>(sG, sA, tid, 150, 160, 160);
  else                relu_fill<AS, true >(sG, sA, tid, 150, 150, 320);
  __syncthreads();

  // L2: 150 -> 100
  mfma_layer<AS>(sA, sG, wave, col, quad, F32 ? 10 : 5, 7, 100,
    [&](int n) { return ldf(b2_, n); },
    [&](int k, int n) -> unsigned short {
      if constexpr (!F32) {
        const unsigned short* w2 = (const unsigned short*)w2_;
        return (k < 150) ? w2[k * 100 + n] : (unsigned short)0;
      } else {
        const float* w2 = (const float*)w2_;
        if (k < 150) return hi_of(w2[k * 100 + n]);
        if (k < 300) return hi_of(w2[(k - 150) * 100 + n]);
        return (unsigned short)0;
      }
    });
  __syncthreads();
  if constexpr (!F32) relu_fill<AS, false>(sG, sA, tid, 100, 128, 128);
  else                relu_fill<AS, true >(sG, sA, tid, 100, 100, 224);
  __syncthreads();

  // L3: 100 -> 100
  mfma_layer<AS>(sA, sG, wave, col, quad, F32 ? 7 : 4, 7, 100,
    [&](int n) { return ldf(b3_, n); },
    [&](int k, int n) -> unsigned short {
      if constexpr (!F32) {
        const unsigned short* w3 = (const unsigned short*)w3_;
        return (k < 100) ? w3[k * 100 + n] : (unsigned short)0;
      } else {
        const float* w3 = (const float*)w3_;
        if (k < 100) return hi_of(w3[k * 100 + n]);
        if (k < 200) return hi_of(w3[(k - 100) * 100 + n]);
        return (unsigned short)0;
      }
    });
  __syncthreads();

  // L4: relu(sG) @ w4 + b4, f32 VALU, 16-lane shuffle reduce (first 256 threads)
  if (tid < 256) {
    int m = tid >> 4, j0 = tid & 15;
    float s = 0.f;
    for (int j = j0; j < 100; j += 16)
      s += fmaxf(sG[j * 20 + m], 0.f) * ldf(w4_, j);
    s += __shfl_xor(s, 8); s += __shfl_xor(s, 4);
    s += __shfl_xor(s, 2); s += __shfl_xor(s, 1);
    if (j0 == 0) {
      float v = s + ldf(b4_, 0);
      if constexpr (!F32) ((unsigned short*)out_)[r0 + m] = f2bf(v);
      else                ((float*)out_)[r0 + m] = v;
    }
  }
}

extern "C" void kernel_launch(void* const* d_in, const int* in_sizes, int n_in,
                              void* d_out, int out_size, void* d_ws, size_t ws_size,
                              hipStream_t stream) {
  (void)in_sizes; (void)n_in; (void)out_size;
  // d_in[1..10] (mlp1_* / attn_*) are dead code in the reference — unused.
  const void* state = d_in[0];
  const void* wih = d_in[11]; const void* whh = d_in[12];
  const void* bih = d_in[13]; const void* bhh = d_in[14];
  const void* w1  = d_in[15]; const void* b1  = d_in[16];
  const void* w2  = d_in[17]; const void* b2  = d_in[18];
  const void* w3  = d_in[19]; const void* b3  = d_in[20];
  const void* w4  = d_in[21]; const void* b4  = d_in[22];

  if (ws_size >= sizeof(int)) {
    int* flag = (int*)d_ws;
    detect_dtype_kernel<<<dim3(1), dim3(64), 0, stream>>>(
        (const unsigned short*)state, flag);
    value_net_kernel<false><<<dim3(512), dim3(512), 0, stream>>>(
        state, wih, whh, bih, bhh, w1, b1, w2, b2, w3, b3, w4, b4, d_out, flag);
    value_net_kernel<true><<<dim3(512), dim3(512), 0, stream>>>(
        state, wih, whh, bih, bhh, w1, b1, w2, b2, w3, b3, w4, b4, d_out, flag);
  } else {
    value_net_kernel<false><<<dim3(512), dim3(512), 0, stream>>>(
        state, wih, whh, bih, bhh, w1, b1, w2, b2, w3, b3, w4, b4, d_out,
        (const int*)nullptr);
  }
}

// Round 4
// 241.244 us; speedup vs baseline: 1.6863x; 1.0106x over previous
//
#include <hip/hip_runtime.h>

typedef __attribute__((ext_vector_type(8))) short short8;
typedef __attribute__((ext_vector_type(4))) float f32x4;
union frag_u { short8 v; unsigned short u[8]; };

__device__ __forceinline__ float bf2f(unsigned short b) {
  unsigned int u = ((unsigned int)b) << 16;
  float f; __builtin_memcpy(&f, &u, 4); return f;
}
__device__ __forceinline__ unsigned short f2bf(float f) {
  unsigned int u; __builtin_memcpy(&u, &f, 4);
  return (unsigned short)((u + 0x7FFFu + ((u >> 16) & 1u)) >> 16);
}
__device__ __forceinline__ unsigned short hi_of(float f) { return f2bf(f); }
__device__ __forceinline__ unsigned short lo_of(float f) {
  unsigned short h = f2bf(f); return f2bf(f - bf2f(h));
}
__device__ __forceinline__ float sigm(float x) {
  return __builtin_amdgcn_rcpf(1.f + __expf(-x));
}
__device__ __forceinline__ float tanh_(float x) {
  return 1.f - 2.f * __builtin_amdgcn_rcpf(1.f + __expf(2.f * x));
}

// dtype detector: even-indexed uint16s of an f32 buffer are uniform mantissa
// halves (mostly insane bf16 exponents); of a bf16 buffer they are N(0,1)
// values (sane exponents 100..140). flag: 0 = bf16, 1 = f32.
__global__ void detect_dtype_kernel(const unsigned short* s, int* flag) {
  if (threadIdx.x == 0 && blockIdx.x == 0) {
    int insane = 0;
    for (int i = 0; i < 64; ++i) {
      unsigned short v = s[2 * i];
      int e = (v >> 7) & 0xFF;
      if (e < 100 || e > 140) insane++;
    }
    *flag = (insane >= 16) ? 1 : 0;
  }
}

// sA(16 x Kpad bf16, stride AS) @ W(K x N) -> sG[n][m]  (G stride 20)
// A-frag: lane holds A[m=lane&15][k=kc*32+quad*8+j]; B-frag: W[k][n=tile*16+(lane&15)]
// C/D: row m = quad*4+reg, col n = lane&15   [verified m89/m91]
// 16 waves: tiles strided by 16.
template <int AS, typename GetB, typename GetW>
__device__ __forceinline__ void mfma_layer(const unsigned short* sA, float* sG,
    int wave, int col, int quad, int kc_n, int ntiles, int N, GetB getb, GetW getw)
{
  for (int tile = wave; tile < ntiles; tile += 16) {
    int n = tile * 16 + col;
    float b = (n < N) ? getb(n) : 0.f;
    f32x4 acc = {b, b, b, b};
    for (int kc = 0; kc < kc_n; ++kc) {
      short8 a = *(const short8*)&sA[col * AS + kc * 32 + quad * 8];
      frag_u w;
      #pragma unroll
      for (int j = 0; j < 8; ++j) {
        int k = kc * 32 + quad * 8 + j;
        w.u[j] = (n < N) ? getw(k, n) : (unsigned short)0;
      }
      acc = __builtin_amdgcn_mfma_f32_16x16x32_bf16(a, w.v, acc, 0, 0, 0);
    }
    *(f32x4*)&sG[n * 20 + quad * 4] = acc;
  }
}

// relu(sG col) -> sA as bf16 hi at [0,N), optional lo at [loOff,loOff+N), zero pad to Kpad
template <int AS, bool LO>
__device__ __forceinline__ void relu_fill(const float* sG, unsigned short* sA,
                                          int tid, int N, int loOff, int Kpad) {
  for (int idx = tid; idx < 16 * Kpad; idx += 1024) {
    int m = idx & 15, n = idx >> 4;
    unsigned short v = 0;
    if (n < N) {
      v = f2bf(fmaxf(sG[n * 20 + m], 0.f));
    } else if (LO && n >= loOff && n < loOff + N) {
      float x = fmaxf(sG[(n - loOff) * 20 + m], 0.f);
      v = lo_of(x);
    }
    sA[m * AS + n] = v;
  }
}

// 1024 threads / 16 waves per block, 16 rows per block, grid = 512.
// Each of the 13 gate-tiles is owned by ONE wave (wf[1][KC] ~24 VGPR), the
// 800 activation items are 1/thread, x-feed lives on the item-free threads
// 800..911. Total work identical to the 512-thread version; resident
// parallelism doubles: 2 blocks/CU x 16 waves = 32 waves/CU (needs <=64
// VGPR -> __launch_bounds__(1024, 8); prior round measured 60 with 2x the
// weight fragments).
template <bool F32>
__global__ __launch_bounds__(1024, 8) void value_net_kernel(
    const void* state_, const void* wih_, const void* whh_,
    const void* bih_, const void* bhh_,
    const void* w1_, const void* b1_, const void* w2_, const void* b2_,
    const void* w3_, const void* b3_, const void* w4_, const void* b4_,
    void* out_, const int* flag)
{
  if (flag && *flag != (F32 ? 1 : 0)) return;   // dtype mismatch -> other variant runs

  // A column layout, LSTM phase:
  //  bf16: [x(0..6) | h_hi(7..56) | h_lo(57..106) | 0-pad..127]           K=4x32
  //  f32 : [x_hi(0..6) | x_lo(7..13) | x_hi(14..20) | h_hi(21..70) |
  //         h_lo(71..120) | h_hi(121..170) | 0-pad..191]                  K=6x32
  //        paired with W rows [Wx_hi|Wx_hi|Wx_lo|Wh_hi|Wh_hi|Wh_lo] (tri-product)
  constexpr int AS = F32 ? 328 : 168;   // max Kpad (+8 pad): f32 L2 needs 320
  constexpr int KC = F32 ? 6 : 4;

  __shared__ __align__(16) unsigned short sA[16 * AS];
  __shared__ __align__(16) float sG[208 * 20];

  const unsigned short* st16 = (const unsigned short*)state_;
  const float*          stf  = (const float*)state_;

  const int tid  = threadIdx.x;
  const int wave = tid >> 6;            // 0..15
  const int lane = tid & 63;
  const int col  = lane & 15;
  const int quad = lane >> 4;
  const int r0   = blockIdx.x * 16;

  // ---- zero sA (h0 = 0 and all K padding) ----
  {
    unsigned int* a32 = (unsigned int*)sA;
    constexpr int ZN = (16 * AS / 2 + 1023) / 1024;
    #pragma unroll
    for (int i = 0; i < ZN; ++i) {
      int idx = tid + i * 1024;
      if (idx < 16 * AS / 2) a32[idx] = 0;
    }
  }

  // ---- LSTM weight getter ----
  auto W_lstm = [&](int k, int n) -> unsigned short {
    if constexpr (!F32) {
      const unsigned short* wih = (const unsigned short*)wih_;
      const unsigned short* whh = (const unsigned short*)whh_;
      if (k < 7)   return wih[k * 200 + n];
      if (k < 57)  return whh[(k - 7) * 200 + n];
      if (k < 107) return whh[(k - 57) * 200 + n];
      return (unsigned short)0;
    } else {
      const float* wih = (const float*)wih_;
      const float* whh = (const float*)whh_;
      if (k < 7)   return hi_of(wih[k * 200 + n]);
      if (k < 14)  return hi_of(wih[(k - 7) * 200 + n]);
      if (k < 21)  return lo_of(wih[(k - 14) * 200 + n]);
      if (k < 71)  return hi_of(whh[(k - 21) * 200 + n]);
      if (k < 121) return hi_of(whh[(k - 71) * 200 + n]);
      if (k < 171) return lo_of(whh[(k - 121) * 200 + n]);
      return (unsigned short)0;
    }
  };
  auto ldf = [&](const void* p, int i) -> float {
    if constexpr (F32) return ((const float*)p)[i];
    else               return bf2f(((const unsigned short*)p)[i]);
  };

  // ---- persistent LSTM weight fragments: 13 N-tiles over 16 waves ----
  const bool hasTile = (wave < 13);
  frag_u wf[KC];
  float  wb = 0.f;
  if (hasTile) {
    int n = wave * 16 + col;
    #pragma unroll
    for (int kc = 0; kc < KC; ++kc) {
      #pragma unroll
      for (int j = 0; j < 8; ++j) {
        int k = kc * 32 + quad * 8 + j;
        wf[kc].u[j] = (n < 200) ? W_lstm(k, n) : (unsigned short)0;
      }
    }
    wb = (n < 200) ? (ldf(bih_, n) + ldf(bhh_, n)) : 0.f;
  }

  // ---- activation work: item idx = u*16 + m, 800 over 1024 threads ----
  const bool iv = tid < 800;
  const int  im = tid & 15, iu = tid >> 4;
  float c_ = 0.f, hf = 0.f;

  // x-feed on item-free threads 800..911 (8 rows x 7 dims x [t])
  const bool isx = (tid >= 800) && (tid < 912);
  const int  xm = (tid - 800) / 7, xd = (tid - 800) - ((tid - 800) / 7) * 7;
  auto xgidx = [&](int t) -> size_t { return (size_t)(r0 + xm) * 832 + t * 13 + 6 + xd; };
  auto xwrite = [&](float fv, unsigned short bv) {
    if constexpr (!F32) { sA[xm * AS + xd] = bv; }
    else {
      unsigned short h = f2bf(fv);
      sA[xm * AS + xd] = h; sA[xm * AS + 14 + xd] = h;
      sA[xm * AS + 7 + xd] = f2bf(fv - bf2f(h));
    }
  };

  unsigned short xv16 = 0; float xvf = 0.f;   // prefetched x_{t+1}

  __syncthreads();
  if (isx) {   // x_0 + prefetch x_1
    if constexpr (!F32) { xwrite(0.f, st16[xgidx(0)]); xv16 = st16[xgidx(1)]; }
    else                { xwrite(stf[xgidx(0)], 0);    xvf  = stf[xgidx(1)]; }
  }
  __syncthreads();

  // ---- LSTM: 64 steps ----
  for (int t = 0; t < 64; ++t) {
    if (hasTile) {
      short8 a[KC];
      #pragma unroll
      for (int kc = 0; kc < KC; ++kc)
        a[kc] = *(const short8*)&sA[col * AS + kc * 32 + quad * 8];
      f32x4 acc = {wb, wb, wb, wb};
      #pragma unroll
      for (int kc = 0; kc < KC; ++kc)
        acc = __builtin_amdgcn_mfma_f32_16x16x32_bf16(a[kc], wf[kc].v, acc, 0, 0, 0);
      int n = wave * 16 + col;
      *(f32x4*)&sG[n * 20 + quad * 4] = acc;
    }
    __syncthreads();
    if (iv) {
      float gi = sG[iu * 20 + im];
      float gf = sG[(50 + iu) * 20 + im];
      float gg = sG[(100 + iu) * 20 + im];
      float go = sG[(150 + iu) * 20 + im];
      float cc = sigm(gf) * c_ + sigm(gi) * tanh_(gg);
      c_ = cc;
      float h = sigm(go) * tanh_(cc);
      if (t < 63) {
        unsigned short hb = f2bf(h);
        unsigned short hl = f2bf(h - bf2f(hb));
        if constexpr (!F32) { sA[im * AS + 7 + iu] = hb; sA[im * AS + 57 + iu] = hl; }
        else { sA[im * AS + 21 + iu] = hb; sA[im * AS + 121 + iu] = hb; sA[im * AS + 71 + iu] = hl; }
      } else hf = h;
    }
    if (isx && t < 63) {
      if constexpr (!F32) xwrite(0.f, xv16); else xwrite(xvf, 0);
      if (t < 62) { if constexpr (!F32) xv16 = st16[xgidx(t + 2)]; else xvf = stf[xgidx(t + 2)]; }
    }
    __syncthreads();
  }

  // ---- tail MLP, fused ----
  // joint cols: bf16 [self(0..5)|h_hi(6..55)|h_lo(56..105)] K=106->128
  //             f32  [self_hi(0..5)|h_hi(6..55)|self_lo(56..61)|h_lo(62..111)] K=112->128
  {
    unsigned int* a32 = (unsigned int*)sA;
    constexpr int ZN = (16 * AS / 2 + 1023) / 1024;
    #pragma unroll
    for (int i = 0; i < ZN; ++i) {
      int idx = tid + i * 1024;
      if (idx < 16 * AS / 2) a32[idx] = 0;
    }
  }
  __syncthreads();
  if (iv) {
    unsigned short hb = f2bf(hf);
    unsigned short hl = f2bf(hf - bf2f(hb));
    sA[im * AS + 6 + iu] = hb;
    if constexpr (!F32) sA[im * AS + 56 + iu] = hl; else sA[im * AS + 62 + iu] = hl;
  }
  if (tid < 96) {
    int m = tid / 6, d = tid - (tid / 6) * 6;
    if constexpr (!F32) sA[m * AS + d] = st16[(size_t)(r0 + m) * 832 + d];
    else {
      float f = stf[(size_t)(r0 + m) * 832 + d];
      sA[m * AS + d] = hi_of(f); sA[m * AS + 56 + d] = lo_of(f);
    }
  }
  __syncthreads();

  // L1: -> 150
  mfma_layer<AS>(sA, sG, wave, col, quad, 4, 10, 150,
    [&](int n) { return ldf(b1_, n); },
    [&](int k, int n) -> unsigned short {
      if constexpr (!F32) {
        const unsigned short* w1 = (const unsigned short*)w1_;
        if (k < 56)  return w1[k * 150 + n];
        if (k < 106) return w1[(k - 50) * 150 + n];
        return (unsigned short)0;
      } else {
        const float* w1 = (const float*)w1_;
        if (k < 56)  return hi_of(w1[k * 150 + n]);
        if (k < 112) return hi_of(w1[(k - 56) * 150 + n]);
        return (unsigned short)0;
      }
    });
  __syncthreads();
  if constexpr (!F32) relu_fill<AS, false>(sG, sA, tid, 150, 160, 160);
  else                relu_fill<AS, true >(sG, sA, tid, 150, 150, 320);
  __syncthreads();

  // L2: 150 -> 100
  mfma_layer<AS>(sA, sG, wave, col, quad, F32 ? 10 : 5, 7, 100,
    [&](int n) { return ldf(b2_, n); },
    [&](int k, int n) -> unsigned short {
      if constexpr (!F32) {
        const unsigned short* w2 = (const unsigned short*)w2_;
        return (k < 150) ? w2[k * 100 + n] : (unsigned short)0;
      } else {
        const float* w2 = (const float*)w2_;
        if (k < 150) return hi_of(w2[k * 100 + n]);
        if (k < 300) return hi_of(w2[(k - 150) * 100 + n]);
        return (unsigned short)0;
      }
    });
  __syncthreads();
  if constexpr (!F32) relu_fill<AS, false>(sG, sA, tid, 100, 128, 128);
  else                relu_fill<AS, true >(sG, sA, tid, 100, 100, 224);
  __syncthreads();

  // L3: 100 -> 100
  mfma_layer<AS>(sA, sG, wave, col, quad, F32 ? 7 : 4, 7, 100,
    [&](int n) { return ldf(b3_, n); },
    [&](int k, int n) -> unsigned short {
      if constexpr (!F32) {
        const unsigned short* w3 = (const unsigned short*)w3_;
        return (k < 100) ? w3[k * 100 + n] : (unsigned short)0;
      } else {
        const float* w3 = (const float*)w3_;
        if (k < 100) return hi_of(w3[k * 100 + n]);
        if (k < 200) return hi_of(w3[(k - 100) * 100 + n]);
        return (unsigned short)0;
      }
    });
  __syncthreads();

  // L4: relu(sG) @ w4 + b4, f32 VALU, 16-lane shuffle reduce (first 256 threads)
  if (tid < 256) {
    int m = tid >> 4, j0 = tid & 15;
    float s = 0.f;
    for (int j = j0; j < 100; j += 16)
      s += fmaxf(sG[j * 20 + m], 0.f) * ldf(w4_, j);
    s += __shfl_xor(s, 8); s += __shfl_xor(s, 4);
    s += __shfl_xor(s, 2); s += __shfl_xor(s, 1);
    if (j0 == 0) {
      float v = s + ldf(b4_, 0);
      if constexpr (!F32) ((unsigned short*)out_)[r0 + m] = f2bf(v);
      else                ((float*)out_)[r0 + m] = v;
    }
  }
}

extern "C" void kernel_launch(void* const* d_in, const int* in_sizes, int n_in,
                              void* d_out, int out_size, void* d_ws, size_t ws_size,
                              hipStream_t stream) {
  (void)in_sizes; (void)n_in; (void)out_size;
  // d_in[1..10] (mlp1_* / attn_*) are dead code in the reference — unused.
  const void* state = d_in[0];
  const void* wih = d_in[11]; const void* whh = d_in[12];
  const void* bih = d_in[13]; const void* bhh = d_in[14];
  const void* w1  = d_in[15]; const void* b1  = d_in[16];
  const void* w2  = d_in[17]; const void* b2  = d_in[18];
  const void* w3  = d_in[19]; const void* b3  = d_in[20];
  const void* w4  = d_in[21]; const void* b4  = d_in[22];

  if (ws_size >= sizeof(int)) {
    int* flag = (int*)d_ws;
    detect_dtype_kernel<<<dim3(1), dim3(64), 0, stream>>>(
        (const unsigned short*)state, flag);
    value_net_kernel<false><<<dim3(512), dim3(1024), 0, stream>>>(
        state, wih, whh, bih, bhh, w1, b1, w2, b2, w3, b3, w4, b4, d_out, flag);
    value_net_kernel<true><<<dim3(512), dim3(1024), 0, stream>>>(
        state, wih, whh, bih, bhh, w1, b1, w2, b2, w3, b3, w4, b4, d_out, flag);
  } else {
    value_net_kernel<false><<<dim3(512), dim3(1024), 0, stream>>>(
        state, wih, whh, bih, bhh, w1, b1, w2, b2, w3, b3, w4, b4, d_out,
        (const int*)nullptr);
  }
}